// Round 1
// baseline (1580.898 us; speedup 1.0000x reference)
//
#include <hip/hip_runtime.h>

// ---------------- constants ----------------
namespace {
constexpr int NN = 50000;   // nodes
constexpr int NE = 800000;  // edges
constexpr int NG = 256;     // graphs
constexpr int NF = 34;      // in features
constexpr int ND = 128;     // hidden
constexpr int NL = 4;       // GAT layers
}
#define EPSB 1e-5f
#define LSLOPE 0.2f
#define INV_SQRT_C 0.17677669529663687f  // 1/sqrt(32)

// ---------------- CSR build ----------------
__global__ void k_deg(const int* __restrict__ ei, int* __restrict__ deg) {
    int e = blockIdx.x * blockDim.x + threadIdx.x;
    if (e < NE) atomicAdd(&deg[ei[NE + e]], 1);
}

__global__ __launch_bounds__(1024) void k_scan(const int* __restrict__ deg, int* __restrict__ rp) {
    __shared__ int sm[1024];
    int t = threadIdx.x;
    const int SEG = (NN + 1023) / 1024;  // 49
    int beg = t * SEG;
    int end = beg + SEG; if (end > NN) end = NN;
    if (beg > NN) beg = NN;
    int s = 0;
    for (int i = beg; i < end; ++i) s += deg[i];
    sm[t] = s;
    __syncthreads();
    for (int off = 1; off < 1024; off <<= 1) {
        int v = (t >= off) ? sm[t - off] : 0;
        __syncthreads();
        sm[t] += v;
        __syncthreads();
    }
    int base = (t == 0) ? 0 : sm[t - 1];
    for (int i = beg; i < end; ++i) { rp[i] = base; base += deg[i]; }
    if (t == 1023) rp[NN] = sm[1023];
}

__global__ void k_fill(const int* __restrict__ ei, int* __restrict__ cursor, int* __restrict__ col) {
    int e = blockIdx.x * blockDim.x + threadIdx.x;
    if (e < NE) {
        int d = ei[NE + e];
        int p = atomicAdd(&cursor[d], 1);
        col[p] = ei[e];
    }
}

// ---------------- GEMM: (n,128) @ (128,128) + bias ----------------
__global__ __launch_bounds__(256) void k_gemm128(const float* __restrict__ A,
                                                 const float* __restrict__ W,
                                                 const float* __restrict__ bias,
                                                 float* __restrict__ out, int nRows) {
    __shared__ float As[64 * 128];
    int r0 = blockIdx.x * 64;
    int rows = nRows - r0; if (rows > 64) rows = 64;
    const float4* A4 = (const float4*)A;
    float4* As4 = (float4*)As;
    for (int idx = threadIdx.x; idx < 64 * 32; idx += 256) {
        int r = idx >> 5;
        float4 v = make_float4(0.f, 0.f, 0.f, 0.f);
        if (r < rows) v = A4[(size_t)(r0 + r) * 32 + (idx & 31)];
        As4[idx] = v;
    }
    __syncthreads();
    int tx = threadIdx.x & 31, ty = threadIdx.x >> 5;
    const float4* W4 = (const float4*)W;
    float acc[8][4];
#pragma unroll
    for (int j = 0; j < 8; ++j)
#pragma unroll
        for (int i = 0; i < 4; ++i) acc[j][i] = 0.f;
#pragma unroll 4
    for (int k = 0; k < 128; ++k) {
        float4 w = W4[k * 32 + tx];
#pragma unroll
        for (int j = 0; j < 8; ++j) {
            float a = As[(ty * 8 + j) * 128 + k];
            acc[j][0] += a * w.x; acc[j][1] += a * w.y;
            acc[j][2] += a * w.z; acc[j][3] += a * w.w;
        }
    }
    float4 b = ((const float4*)bias)[tx];
#pragma unroll
    for (int j = 0; j < 8; ++j) {
        int r = ty * 8 + j;
        if (r < rows) {
            float4 o = make_float4(acc[j][0] + b.x, acc[j][1] + b.y,
                                   acc[j][2] + b.z, acc[j][3] + b.w);
            ((float4*)out)[(size_t)(r0 + r) * 32 + tx] = o;
        }
    }
}

// ---------------- GEMM: (n,34) @ (34,128) + bias ----------------
__global__ __launch_bounds__(256) void k_gemm_emb(const float* __restrict__ A,
                                                  const float* __restrict__ W,
                                                  const float* __restrict__ bias,
                                                  float* __restrict__ out, int nRows) {
    __shared__ float As[64 * NF];
    int r0 = blockIdx.x * 64;
    int rows = nRows - r0; if (rows > 64) rows = 64;
    int total = rows * NF;
    for (int idx = threadIdx.x; idx < 64 * NF; idx += 256)
        As[idx] = (idx < total) ? A[(size_t)r0 * NF + idx] : 0.f;
    __syncthreads();
    int tx = threadIdx.x & 31, ty = threadIdx.x >> 5;
    const float4* W4 = (const float4*)W;
    float acc[8][4];
#pragma unroll
    for (int j = 0; j < 8; ++j)
#pragma unroll
        for (int i = 0; i < 4; ++i) acc[j][i] = 0.f;
#pragma unroll 2
    for (int k = 0; k < NF; ++k) {
        float4 w = W4[k * 32 + tx];
#pragma unroll
        for (int j = 0; j < 8; ++j) {
            float a = As[(ty * 8 + j) * NF + k];
            acc[j][0] += a * w.x; acc[j][1] += a * w.y;
            acc[j][2] += a * w.z; acc[j][3] += a * w.w;
        }
    }
    float4 b = ((const float4*)bias)[tx];
#pragma unroll
    for (int j = 0; j < 8; ++j) {
        int r = ty * 8 + j;
        if (r < rows) {
            float4 o = make_float4(acc[j][0] + b.x, acc[j][1] + b.y,
                                   acc[j][2] + b.z, acc[j][3] + b.w);
            ((float4*)out)[(size_t)(r0 + r) * 32 + tx] = o;
        }
    }
}

// ---------------- BN statistics (per-column sum / sumsq) ----------------
__global__ __launch_bounds__(256) void k_stats(const float* __restrict__ src, int nRows,
                                               float* __restrict__ st) {
    int c = threadIdx.x & 127;
    int sub = threadIdx.x >> 7;  // 0/1
    int r0 = blockIdx.x * 256;
    int rend = r0 + 256; if (rend > nRows) rend = nRows;
    float s = 0.f, ss = 0.f;
    for (int r = r0 + sub; r < rend; r += 2) {
        float v = src[(size_t)r * 128 + c];
        s += v; ss += v * v;
    }
    atomicAdd(&st[c], s);
    atomicAdd(&st[128 + c], ss);
}

__global__ __launch_bounds__(128) void k_finalize(const float* __restrict__ st,
                                                  const float* __restrict__ g,
                                                  const float* __restrict__ b,
                                                  float invn, float* __restrict__ scsh) {
    int c = threadIdx.x;
    float mean = st[c] * invn;
    float var = st[128 + c] * invn - mean * mean;
    var = fmaxf(var, 0.f);
    float sc = g[c] * rsqrtf(var + EPSB);
    scsh[c] = sc;
    scsh[128 + c] = b[c] - mean * sc;
}

// dst = (doRes ? dst : 0) + maybe_relu(src*scale + shift)
__global__ __launch_bounds__(256) void k_bn_apply(float* __restrict__ dst,
                                                  const float* __restrict__ src,
                                                  const float* __restrict__ scsh,
                                                  int doRelu, int doRes) {
    const float4* s4 = (const float4*)src;
    const float4* sc4 = (const float4*)scsh;
    const float4* sh4 = sc4 + 32;
    float4* d4 = (float4*)dst;
    const int total = NN * 32;
    for (int i = blockIdx.x * blockDim.x + threadIdx.x; i < total; i += gridDim.x * blockDim.x) {
        float4 v = s4[i];
        float4 a = sc4[i & 31], b = sh4[i & 31];
        v.x = v.x * a.x + b.x; v.y = v.y * a.y + b.y;
        v.z = v.z * a.z + b.z; v.w = v.w * a.w + b.w;
        if (doRelu) {
            v.x = fmaxf(v.x, 0.f); v.y = fmaxf(v.y, 0.f);
            v.z = fmaxf(v.z, 0.f); v.w = fmaxf(v.w, 0.f);
        }
        if (doRes) {
            float4 o = d4[i];
            v.x += o.x; v.y += o.y; v.z += o.z; v.w += o.w;
        }
        d4[i] = v;
    }
}

// ---------------- GATv2 fused edge pass (one wave per node, online softmax) --------
// lane handles channels c=2*lane, 2*lane+1; head h = lane>>4; self-loop appended.
__global__ __launch_bounds__(256) void k_gat_edge(const float* __restrict__ xl,
                                                  const float* __restrict__ xr,
                                                  const float* __restrict__ gatt_l,
                                                  const float* __restrict__ gbias_l,
                                                  const int* __restrict__ rp,
                                                  const int* __restrict__ col,
                                                  float* __restrict__ out) {
    int lane = threadIdx.x & 63;
    int node = blockIdx.x * 4 + (threadIdx.x >> 6);
    if (node >= NN) return;
    int c = lane * 2;
    float2 xr2 = *(const float2*)&xr[(size_t)node * 128 + c];
    float2 ga = *(const float2*)&gatt_l[c];
    float2 gb = *(const float2*)&gbias_l[c];
    float m = -INFINITY, l = 0.f, ax = 0.f, ay = 0.f;
    int s0 = rp[node], s1 = rp[node + 1];
    int nEd = s1 - s0;  // real in-edges; iteration nEd is the self-loop
    int sCur = (nEd > 0) ? col[s0] : node;
    float2 xs = *(const float2*)&xl[(size_t)sCur * 128 + c];
    for (int i = 0; i <= nEd; ++i) {
        int sNxt = (i + 1 < nEd) ? col[s0 + i + 1] : node;
        float2 xsN = *(const float2*)&xl[(size_t)sNxt * 128 + c];  // prefetch
        float ex = xs.x + xr2.x; ex = (ex > 0.f) ? ex : LSLOPE * ex;
        float ey = xs.y + xr2.y; ey = (ey > 0.f) ? ey : LSLOPE * ey;
        float p = ex * ga.x + ey * ga.y;
        p += __shfl_xor(p, 1); p += __shfl_xor(p, 2);
        p += __shfl_xor(p, 4); p += __shfl_xor(p, 8);
        float nm = fmaxf(m, p);
        float al = __expf(m - nm);
        float w = __expf(p - nm);
        l = l * al + w;
        ax = ax * al + w * xs.x;
        ay = ay * al + w * xs.y;
        m = nm;
        xs = xsN;
    }
    float inv = 1.f / (l + 1e-16f);
    float2 o = make_float2(ax * inv + gb.x, ay * inv + gb.y);
    *(float2*)&out[(size_t)node * 128 + c] = o;
}

// ---------------- TransformerConv fused edge pass (no self loops) ----------------
__global__ __launch_bounds__(256) void k_trans_edge(const float* __restrict__ q,
                                                    const float* __restrict__ kk,
                                                    const float* __restrict__ vv,
                                                    const float* __restrict__ sT,
                                                    const int* __restrict__ rp,
                                                    const int* __restrict__ col,
                                                    float* __restrict__ zout) {
    int lane = threadIdx.x & 63;
    int node = blockIdx.x * 4 + (threadIdx.x >> 6);
    if (node >= NN) return;
    int c = lane * 2;
    float2 q2 = *(const float2*)&q[(size_t)node * 128 + c];
    q2.x *= INV_SQRT_C; q2.y *= INV_SQRT_C;
    float m = -INFINITY, l = 0.f, ax = 0.f, ay = 0.f;
    int s0 = rp[node], s1 = rp[node + 1];
    int nEd = s1 - s0;
    int sCur = (nEd > 0) ? col[s0] : 0;
    float2 k2 = *(const float2*)&kk[(size_t)sCur * 128 + c];
    float2 v2 = *(const float2*)&vv[(size_t)sCur * 128 + c];
    for (int i = 0; i < nEd; ++i) {
        int sNxt = (i + 1 < nEd) ? col[s0 + i + 1] : sCur;
        float2 k2n = *(const float2*)&kk[(size_t)sNxt * 128 + c];
        float2 v2n = *(const float2*)&vv[(size_t)sNxt * 128 + c];
        float p = q2.x * k2.x + q2.y * k2.y;
        p += __shfl_xor(p, 1); p += __shfl_xor(p, 2);
        p += __shfl_xor(p, 4); p += __shfl_xor(p, 8);
        float nm = fmaxf(m, p);
        float al = __expf(m - nm);
        float w = __expf(p - nm);
        l = l * al + w;
        ax = ax * al + w * v2.x;
        ay = ay * al + w * v2.y;
        m = nm;
        k2 = k2n; v2 = v2n;
    }
    float inv = 1.f / (l + 1e-16f);
    float2 st2 = *(const float2*)&sT[(size_t)node * 128 + c];
    float2 o = make_float2(ax * inv + st2.x, ay * inv + st2.y);
    *(float2*)&zout[(size_t)node * 128 + c] = o;
}

// ---------------- pooling: per-graph mean + max (batch sorted) ----------------
__global__ __launch_bounds__(128) void k_pool(const float* __restrict__ x,
                                              const int* __restrict__ batch,
                                              float* __restrict__ h) {
    int g = blockIdx.x;
    int lo = 0, hi = NN;
    while (lo < hi) { int mid = (lo + hi) >> 1; if (batch[mid] < g) lo = mid + 1; else hi = mid; }
    int start = lo;
    hi = NN;
    while (lo < hi) { int mid = (lo + hi) >> 1; if (batch[mid] < g + 1) lo = mid + 1; else hi = mid; }
    int end = lo;
    int c = threadIdx.x;
    float s = 0.f, mx = -INFINITY;
    for (int r = start; r < end; ++r) {
        float v = x[(size_t)r * 128 + c];
        s += v; mx = fmaxf(mx, v);
    }
    int cnt = end - start;
    float xm = s / fmaxf((float)cnt, 1.f);
    float xx = (cnt > 0) ? mx : 0.f;
    h[g * 256 + c] = xm;
    h[g * 256 + 128 + c] = xx;
}

// ---------------- head ----------------
__global__ __launch_bounds__(128) void k_head1(const float* __restrict__ h,
                                               const float* __restrict__ W,
                                               const float* __restrict__ b,
                                               float* __restrict__ t1) {
    __shared__ float hr[256];
    int row = blockIdx.x;
    int t = threadIdx.x;
    hr[t] = h[row * 256 + t];
    hr[t + 128] = h[row * 256 + 128 + t];
    __syncthreads();
    float acc = b[t];
#pragma unroll 4
    for (int k = 0; k < 256; ++k) acc += hr[k] * W[k * 128 + t];
    t1[row * 128 + t] = acc;
}

__global__ __launch_bounds__(64) void k_head2(const float* __restrict__ t1,
                                              const float* __restrict__ scsh,
                                              const float* __restrict__ W2,
                                              const float* __restrict__ b2,
                                              const float* __restrict__ W3,
                                              const float* __restrict__ b3,
                                              float* __restrict__ out) {
    __shared__ float v[128];
    int row = blockIdx.x, t = threadIdx.x;
    {
        float a = t1[row * 128 + t] * scsh[t] + scsh[128 + t];
        v[t] = fmaxf(a, 0.f);
        float a2 = t1[row * 128 + 64 + t] * scsh[64 + t] + scsh[192 + t];
        v[64 + t] = fmaxf(a2, 0.f);
    }
    __syncthreads();
    float acc = b2[t];
#pragma unroll 4
    for (int k = 0; k < 128; ++k) acc += v[k] * W2[k * 64 + t];
    float p = fmaxf(acc, 0.f) * W3[t];
    p += __shfl_xor(p, 1); p += __shfl_xor(p, 2); p += __shfl_xor(p, 4);
    p += __shfl_xor(p, 8); p += __shfl_xor(p, 16); p += __shfl_xor(p, 32);
    if (t == 0) out[row] = p + b3[0];
}

// ---------------- launch ----------------
extern "C" void kernel_launch(void* const* d_in, const int* in_sizes, int n_in,
                              void* d_out, int out_size, void* d_ws, size_t ws_size,
                              hipStream_t stream) {
    const float* x_in   = (const float*)d_in[0];
    const int*   ei     = (const int*)d_in[1];
    const int*   batch  = (const int*)d_in[2];
    const float* emb_W  = (const float*)d_in[3];
    const float* emb_b  = (const float*)d_in[4];
    const float* emb_g  = (const float*)d_in[5];
    const float* emb_be = (const float*)d_in[6];
    const float* gWl    = (const float*)d_in[7];
    const float* gWr    = (const float*)d_in[8];
    const float* gbl    = (const float*)d_in[9];
    const float* gbr    = (const float*)d_in[10];
    const float* gatt   = (const float*)d_in[11];
    const float* gbias  = (const float*)d_in[12];
    const float* gg     = (const float*)d_in[13];
    const float* gbe    = (const float*)d_in[14];
    const float* tWq    = (const float*)d_in[15];
    const float* tWk    = (const float*)d_in[16];
    const float* tWv    = (const float*)d_in[17];
    const float* tWs    = (const float*)d_in[18];
    const float* tbq    = (const float*)d_in[19];
    const float* tbk    = (const float*)d_in[20];
    const float* tbv    = (const float*)d_in[21];
    const float* tbs    = (const float*)d_in[22];
    const float* tg     = (const float*)d_in[23];
    const float* tbe    = (const float*)d_in[24];
    const float* oW1    = (const float*)d_in[25];
    const float* ob1    = (const float*)d_in[26];
    const float* og     = (const float*)d_in[27];
    const float* obe    = (const float*)d_in[28];
    const float* oW2    = (const float*)d_in[29];
    const float* ob2    = (const float*)d_in[30];
    const float* oW3    = (const float*)d_in[31];
    const float* ob3    = (const float*)d_in[32];
    float* out = (float*)d_out;

    const size_t NDsz = (size_t)NN * 128;
    float* x     = (float*)d_ws;
    float* bA    = x + NDsz;
    float* bB    = bA + NDsz;
    float* bC    = bB + NDsz;
    float* bD    = bC + NDsz;
    float* stats = bD + NDsz;        // 7 * 256 floats
    float* scsh  = stats + 7 * 256;  // 256 floats
    float* hpool = scsh + 256;       // 256*256
    float* t1    = hpool + 65536;    // 256*128
    int* deg     = (int*)(t1 + 32768);
    int* rp      = deg + NN;
    int* cursor  = rp + NN + 1;
    int* colb    = cursor + NN;

    hipMemsetAsync(deg, 0, NN * sizeof(int), stream);
    hipMemsetAsync(stats, 0, 7 * 256 * sizeof(float), stream);

    // CSR by destination
    k_deg<<<(NE + 255) / 256, 256, 0, stream>>>(ei, deg);
    k_scan<<<1, 1024, 0, stream>>>(deg, rp);
    hipMemcpyAsync(cursor, rp, NN * sizeof(int), hipMemcpyDeviceToDevice, stream);
    k_fill<<<(NE + 255) / 256, 256, 0, stream>>>(ei, cursor, colb);

    const int gGemm = (NN + 63) / 64;
    const int gStat = (NN + 255) / 256;
    const int gEdge = (NN + 3) / 4;

    // embedding + BN + relu
    k_gemm_emb<<<gGemm, 256, 0, stream>>>(x_in, emb_W, emb_b, bA, NN);
    k_stats<<<gStat, 256, 0, stream>>>(bA, NN, stats);
    k_finalize<<<1, 128, 0, stream>>>(stats, emb_g, emb_be, 1.f / NN, scsh);
    k_bn_apply<<<1024, 256, 0, stream>>>(x, bA, scsh, 1, 0);

    // 4 GATv2 layers
    for (int l = 0; l < NL; ++l) {
        k_gemm128<<<gGemm, 256, 0, stream>>>(x, gWl + (size_t)l * 16384, gbl + l * 128, bA, NN);
        k_gemm128<<<gGemm, 256, 0, stream>>>(x, gWr + (size_t)l * 16384, gbr + l * 128, bB, NN);
        k_gat_edge<<<gEdge, 256, 0, stream>>>(bA, bB, gatt + l * 128, gbias + l * 128, rp, colb, bC);
        k_stats<<<gStat, 256, 0, stream>>>(bC, NN, stats + (1 + l) * 256);
        k_finalize<<<1, 128, 0, stream>>>(stats + (1 + l) * 256, gg + l * 128, gbe + l * 128, 1.f / NN, scsh);
        k_bn_apply<<<1024, 256, 0, stream>>>(x, bC, scsh, 1, 1);
    }

    // TransformerConv
    k_gemm128<<<gGemm, 256, 0, stream>>>(x, tWq, tbq, bA, NN);
    k_gemm128<<<gGemm, 256, 0, stream>>>(x, tWk, tbk, bB, NN);
    k_gemm128<<<gGemm, 256, 0, stream>>>(x, tWv, tbv, bC, NN);
    k_gemm128<<<gGemm, 256, 0, stream>>>(x, tWs, tbs, bD, NN);
    k_trans_edge<<<gEdge, 256, 0, stream>>>(bA, bB, bC, bD, rp, colb, bA);
    k_stats<<<gStat, 256, 0, stream>>>(bA, NN, stats + 5 * 256);
    k_finalize<<<1, 128, 0, stream>>>(stats + 5 * 256, tg, tbe, 1.f / NN, scsh);
    k_bn_apply<<<1024, 256, 0, stream>>>(x, bA, scsh, 0, 1);

    // pooling + head
    k_pool<<<NG, 128, 0, stream>>>(x, batch, hpool);
    k_head1<<<NG, 128, 0, stream>>>(hpool, oW1, ob1, t1);
    k_stats<<<1, 256, 0, stream>>>(t1, NG, stats + 6 * 256);
    k_finalize<<<1, 128, 0, stream>>>(stats + 6 * 256, og, obe, 1.f / NG, scsh);
    k_head2<<<NG, 64, 0, stream>>>(t1, scsh, oW2, ob2, oW3, ob3, out);
}

// Round 2
// 1430.515 us; speedup vs baseline: 1.1051x; 1.1051x over previous
//
#include <hip/hip_runtime.h>
#include <hip/hip_fp16.h>

// ---------------- constants ----------------
namespace {
constexpr int NN = 50000;   // nodes
constexpr int NE = 800000;  // edges
constexpr int NG = 256;     // graphs
constexpr int NF = 34;      // in features
constexpr int NL = 4;       // GAT layers
}
#define EPSB 1e-5f
#define LSLOPE 0.2f
#define INV_SQRT_C 0.17677669529663687f  // 1/sqrt(32)

typedef short bf16x8 __attribute__((ext_vector_type(8)));
typedef float f32x4 __attribute__((ext_vector_type(4)));

static __device__ __forceinline__ short f2bf(float f) {
    unsigned int u = __float_as_uint(f);
    u = (u + 0x7fff + ((u >> 16) & 1)) >> 16;  // RNE
    return (short)u;
}

// ---------------- CSR build ----------------
__global__ void k_deg(const int* __restrict__ ei, int* __restrict__ deg) {
    int e = blockIdx.x * blockDim.x + threadIdx.x;
    if (e < NE) atomicAdd(&deg[ei[NE + e]], 1);
}

__global__ __launch_bounds__(1024) void k_scan(const int* __restrict__ deg, int* __restrict__ rp) {
    __shared__ int sm[1024];
    int t = threadIdx.x;
    const int SEG = (NN + 1023) / 1024;  // 49
    int beg = t * SEG;
    int end = beg + SEG; if (end > NN) end = NN;
    if (beg > NN) beg = NN;
    int s = 0;
    for (int i = beg; i < end; ++i) s += deg[i];
    sm[t] = s;
    __syncthreads();
    for (int off = 1; off < 1024; off <<= 1) {
        int v = (t >= off) ? sm[t - off] : 0;
        __syncthreads();
        sm[t] += v;
        __syncthreads();
    }
    int base = (t == 0) ? 0 : sm[t - 1];
    for (int i = beg; i < end; ++i) { rp[i] = base; base += deg[i]; }
    if (t == 1023) rp[NN] = sm[1023];
}

__global__ void k_fill(const int* __restrict__ ei, int* __restrict__ cursor, int* __restrict__ col) {
    int e = blockIdx.x * blockDim.x + threadIdx.x;
    if (e < NE) {
        int d = ei[NE + e];
        int p = atomicAdd(&cursor[d], 1);
        col[p] = ei[e];
    }
}

// ---------------- weight prep: 12x (128,128) fp32 -> transposed bf16 ----------------
__global__ __launch_bounds__(256) void k_prep(const float* __restrict__ gWl,
                                              const float* __restrict__ gWr,
                                              const float* __restrict__ tWq,
                                              const float* __restrict__ tWk,
                                              const float* __restrict__ tWv,
                                              const float* __restrict__ tWs,
                                              short* __restrict__ dst) {
    int m = blockIdx.x;
    const float* src;
    if (m < 4) src = gWl + m * 16384;
    else if (m < 8) src = gWr + (m - 4) * 16384;
    else if (m == 8) src = tWq;
    else if (m == 9) src = tWk;
    else if (m == 10) src = tWv;
    else src = tWs;
    short* d = dst + m * 16384;
    for (int i = threadIdx.x; i < 16384; i += 256) {
        int n = i >> 7, k = i & 127;
        d[i] = f2bf(src[k * 128 + n]);  // Wt[n][k] = W[k][n]
    }
}

// ---------------- MFMA GEMM: (n,128)fp32 @ Wt(bf16,transposed) + bias ----------------
// OUTH=1: store __half, OUTH=0: store float
template <int OUTH>
__global__ __launch_bounds__(256) void k_gemm_mfma(const float* __restrict__ A,
                                                   const short* __restrict__ Wt,
                                                   const float* __restrict__ bias,
                                                   void* __restrict__ outP, int nRows) {
    __shared__ short As[64 * 136];
    __shared__ short Bs[128 * 136];
    int r0 = blockIdx.x * 64;
    int rows = nRows - r0; if (rows > 64) rows = 64;
    // stage Wt (bf16, [n][k]) into padded LDS
    const int4* Wt4 = (const int4*)Wt;  // 8 shorts per int4
    for (int idx = threadIdx.x; idx < 2048; idx += 256) {
        int row = idx >> 4, c8 = idx & 15;
        *(int4*)&Bs[row * 136 + c8 * 8] = Wt4[idx];
    }
    // stage A (fp32 -> bf16) into padded LDS
    for (int idx = threadIdx.x; idx < 2048; idx += 256) {
        int r = idx >> 5, c4 = idx & 31;
        float4 v = make_float4(0.f, 0.f, 0.f, 0.f);
        if (r < rows) v = ((const float4*)A)[(size_t)(r0 + r) * 32 + c4];
        short4 s;
        s.x = f2bf(v.x); s.y = f2bf(v.y); s.z = f2bf(v.z); s.w = f2bf(v.w);
        *(short4*)&As[r * 136 + c4 * 4] = s;
    }
    __syncthreads();
    int lane = threadIdx.x & 63, wave = threadIdx.x >> 6;
    int n16 = lane & 15, quad = lane >> 4;
    int arow = wave * 16 + n16;
    bf16x8 af[4];
#pragma unroll
    for (int kc = 0; kc < 4; ++kc)
        af[kc] = *(const bf16x8*)&As[arow * 136 + kc * 32 + quad * 8];
    f32x4 acc[8];
#pragma unroll
    for (int ct = 0; ct < 8; ++ct) acc[ct] = (f32x4){0.f, 0.f, 0.f, 0.f};
#pragma unroll
    for (int ct = 0; ct < 8; ++ct) {
#pragma unroll
        for (int kc = 0; kc < 4; ++kc) {
            bf16x8 bf = *(const bf16x8*)&Bs[(ct * 16 + n16) * 136 + kc * 32 + quad * 8];
            acc[ct] = __builtin_amdgcn_mfma_f32_16x16x32_bf16(af[kc], bf, acc[ct], 0, 0, 0);
        }
    }
#pragma unroll
    for (int ct = 0; ct < 8; ++ct) {
        int col = ct * 16 + n16;
        float b = bias[col];
#pragma unroll
        for (int reg = 0; reg < 4; ++reg) {
            int r = wave * 16 + quad * 4 + reg;  // C/D: col=lane&15, row=quad*4+reg
            if (r < rows) {
                float v = acc[ct][reg] + b;
                if (OUTH)
                    ((__half*)outP)[(size_t)(r0 + r) * 128 + col] = __float2half(v);
                else
                    ((float*)outP)[(size_t)(r0 + r) * 128 + col] = v;
            }
        }
    }
}

// ---------------- GEMM: (n,34) @ (34,128) + bias (fp32 VALU, one dispatch) ----------
__global__ __launch_bounds__(256) void k_gemm_emb(const float* __restrict__ A,
                                                  const float* __restrict__ W,
                                                  const float* __restrict__ bias,
                                                  float* __restrict__ out, int nRows) {
    __shared__ float As[64 * NF];
    int r0 = blockIdx.x * 64;
    int rows = nRows - r0; if (rows > 64) rows = 64;
    int total = rows * NF;
    for (int idx = threadIdx.x; idx < 64 * NF; idx += 256)
        As[idx] = (idx < total) ? A[(size_t)r0 * NF + idx] : 0.f;
    __syncthreads();
    int tx = threadIdx.x & 31, ty = threadIdx.x >> 5;
    const float4* W4 = (const float4*)W;
    float acc[8][4];
#pragma unroll
    for (int j = 0; j < 8; ++j)
#pragma unroll
        for (int i = 0; i < 4; ++i) acc[j][i] = 0.f;
#pragma unroll 2
    for (int k = 0; k < NF; ++k) {
        float4 w = W4[k * 32 + tx];
#pragma unroll
        for (int j = 0; j < 8; ++j) {
            float a = As[(ty * 8 + j) * NF + k];
            acc[j][0] += a * w.x; acc[j][1] += a * w.y;
            acc[j][2] += a * w.z; acc[j][3] += a * w.w;
        }
    }
    float4 b = ((const float4*)bias)[tx];
#pragma unroll
    for (int j = 0; j < 8; ++j) {
        int r = ty * 8 + j;
        if (r < rows) {
            float4 o = make_float4(acc[j][0] + b.x, acc[j][1] + b.y,
                                   acc[j][2] + b.z, acc[j][3] + b.w);
            ((float4*)out)[(size_t)(r0 + r) * 32 + tx] = o;
        }
    }
}

// ---------------- BN statistics (per-column sum / sumsq) ----------------
__global__ __launch_bounds__(256) void k_stats(const float* __restrict__ src, int nRows,
                                               float* __restrict__ st) {
    int c = threadIdx.x & 127;
    int sub = threadIdx.x >> 7;  // 0/1
    int r0 = blockIdx.x * 256;
    int rend = r0 + 256; if (rend > nRows) rend = nRows;
    float s = 0.f, ss = 0.f;
    for (int r = r0 + sub; r < rend; r += 2) {
        float v = src[(size_t)r * 128 + c];
        s += v; ss += v * v;
    }
    atomicAdd(&st[c], s);
    atomicAdd(&st[128 + c], ss);
}

__global__ __launch_bounds__(128) void k_finalize(const float* __restrict__ st,
                                                  const float* __restrict__ g,
                                                  const float* __restrict__ b,
                                                  float invn, float* __restrict__ scsh) {
    int c = threadIdx.x;
    float mean = st[c] * invn;
    float var = st[128 + c] * invn - mean * mean;
    var = fmaxf(var, 0.f);
    float sc = g[c] * rsqrtf(var + EPSB);
    scsh[c] = sc;
    scsh[128 + c] = b[c] - mean * sc;
}

// dst = (doRes ? dst : 0) + maybe_relu(src*scale + shift)
__global__ __launch_bounds__(256) void k_bn_apply(float* __restrict__ dst,
                                                  const float* __restrict__ src,
                                                  const float* __restrict__ scsh,
                                                  int doRelu, int doRes) {
    const float4* s4 = (const float4*)src;
    const float4* sc4 = (const float4*)scsh;
    const float4* sh4 = sc4 + 32;
    float4* d4 = (float4*)dst;
    const int total = NN * 32;
    for (int i = blockIdx.x * blockDim.x + threadIdx.x; i < total; i += gridDim.x * blockDim.x) {
        float4 v = s4[i];
        float4 a = sc4[i & 31], b = sh4[i & 31];
        v.x = v.x * a.x + b.x; v.y = v.y * a.y + b.y;
        v.z = v.z * a.z + b.z; v.w = v.w * a.w + b.w;
        if (doRelu) {
            v.x = fmaxf(v.x, 0.f); v.y = fmaxf(v.y, 0.f);
            v.z = fmaxf(v.z, 0.f); v.w = fmaxf(v.w, 0.f);
        }
        if (doRes) {
            float4 o = d4[i];
            v.x += o.x; v.y += o.y; v.z += o.z; v.w += o.w;
        }
        d4[i] = v;
    }
}

// ---------------- GATv2 fused edge pass (one wave per node, online softmax) --------
// lane handles channels c=2*lane, 2*lane+1; head h = lane>>4; self-loop appended.
__global__ __launch_bounds__(256) void k_gat_edge(const __half* __restrict__ xl,
                                                  const float* __restrict__ xr,
                                                  const float* __restrict__ gatt_l,
                                                  const float* __restrict__ gbias_l,
                                                  const int* __restrict__ rp,
                                                  const int* __restrict__ col,
                                                  float* __restrict__ out) {
    int lane = threadIdx.x & 63;
    int node = blockIdx.x * 4 + (threadIdx.x >> 6);
    if (node >= NN) return;
    int c = lane * 2;
    const __half2* xl2 = (const __half2*)xl;
    float2 xr2 = *(const float2*)&xr[(size_t)node * 128 + c];
    float2 ga = *(const float2*)&gatt_l[c];
    float2 gb = *(const float2*)&gbias_l[c];
    float m = -INFINITY, l = 0.f, ax = 0.f, ay = 0.f;
    int s0 = rp[node], s1 = rp[node + 1];
    int nEd = s1 - s0;  // real in-edges; iteration nEd is the self-loop
    int sCur = (nEd > 0) ? col[s0] : node;
    float2 xs = __half22float2(xl2[(size_t)sCur * 64 + lane]);
    for (int i = 0; i <= nEd; ++i) {
        int sNxt = (i + 1 < nEd) ? col[s0 + i + 1] : node;
        float2 xsN = __half22float2(xl2[(size_t)sNxt * 64 + lane]);  // prefetch
        float ex = xs.x + xr2.x; ex = (ex > 0.f) ? ex : LSLOPE * ex;
        float ey = xs.y + xr2.y; ey = (ey > 0.f) ? ey : LSLOPE * ey;
        float p = ex * ga.x + ey * ga.y;
        p += __shfl_xor(p, 1); p += __shfl_xor(p, 2);
        p += __shfl_xor(p, 4); p += __shfl_xor(p, 8);
        float nm = fmaxf(m, p);
        float al = __expf(m - nm);
        float w = __expf(p - nm);
        l = l * al + w;
        ax = ax * al + w * xs.x;
        ay = ay * al + w * xs.y;
        m = nm;
        xs = xsN;
    }
    float inv = 1.f / (l + 1e-16f);
    float2 o = make_float2(ax * inv + gb.x, ay * inv + gb.y);
    *(float2*)&out[(size_t)node * 128 + c] = o;
}

// ---------------- TransformerConv fused edge pass (no self loops) ----------------
__global__ __launch_bounds__(256) void k_trans_edge(const float* __restrict__ q,
                                                    const __half* __restrict__ kk,
                                                    const __half* __restrict__ vv,
                                                    const float* __restrict__ sT,
                                                    const int* __restrict__ rp,
                                                    const int* __restrict__ col,
                                                    float* __restrict__ zout) {
    int lane = threadIdx.x & 63;
    int node = blockIdx.x * 4 + (threadIdx.x >> 6);
    if (node >= NN) return;
    int c = lane * 2;
    const __half2* k2p = (const __half2*)kk;
    const __half2* v2p = (const __half2*)vv;
    float2 q2 = *(const float2*)&q[(size_t)node * 128 + c];
    q2.x *= INV_SQRT_C; q2.y *= INV_SQRT_C;
    float m = -INFINITY, l = 0.f, ax = 0.f, ay = 0.f;
    int s0 = rp[node], s1 = rp[node + 1];
    int nEd = s1 - s0;
    int sCur = (nEd > 0) ? col[s0] : 0;
    float2 k2 = __half22float2(k2p[(size_t)sCur * 64 + lane]);
    float2 v2 = __half22float2(v2p[(size_t)sCur * 64 + lane]);
    for (int i = 0; i < nEd; ++i) {
        int sNxt = (i + 1 < nEd) ? col[s0 + i + 1] : sCur;
        float2 k2n = __half22float2(k2p[(size_t)sNxt * 64 + lane]);
        float2 v2n = __half22float2(v2p[(size_t)sNxt * 64 + lane]);
        float p = q2.x * k2.x + q2.y * k2.y;
        p += __shfl_xor(p, 1); p += __shfl_xor(p, 2);
        p += __shfl_xor(p, 4); p += __shfl_xor(p, 8);
        float nm = fmaxf(m, p);
        float al = __expf(m - nm);
        float w = __expf(p - nm);
        l = l * al + w;
        ax = ax * al + w * v2.x;
        ay = ay * al + w * v2.y;
        m = nm;
        k2 = k2n; v2 = v2n;
    }
    float inv = 1.f / (l + 1e-16f);
    float2 st2 = *(const float2*)&sT[(size_t)node * 128 + c];
    float2 o = make_float2(ax * inv + st2.x, ay * inv + st2.y);
    *(float2*)&zout[(size_t)node * 128 + c] = o;
}

// ---------------- pooling: per-graph mean + max (batch sorted) ----------------
__global__ __launch_bounds__(128) void k_pool(const float* __restrict__ x,
                                              const int* __restrict__ batch,
                                              float* __restrict__ h) {
    int g = blockIdx.x;
    int lo = 0, hi = NN;
    while (lo < hi) { int mid = (lo + hi) >> 1; if (batch[mid] < g) lo = mid + 1; else hi = mid; }
    int start = lo;
    hi = NN;
    while (lo < hi) { int mid = (lo + hi) >> 1; if (batch[mid] < g + 1) lo = mid + 1; else hi = mid; }
    int end = lo;
    int c = threadIdx.x;
    float s = 0.f, mx = -INFINITY;
    for (int r = start; r < end; ++r) {
        float v = x[(size_t)r * 128 + c];
        s += v; mx = fmaxf(mx, v);
    }
    int cnt = end - start;
    float xm = s / fmaxf((float)cnt, 1.f);
    float xx = (cnt > 0) ? mx : 0.f;
    h[g * 256 + c] = xm;
    h[g * 256 + 128 + c] = xx;
}

// ---------------- head ----------------
__global__ __launch_bounds__(128) void k_head1(const float* __restrict__ h,
                                               const float* __restrict__ W,
                                               const float* __restrict__ b,
                                               float* __restrict__ t1) {
    __shared__ float hr[256];
    int row = blockIdx.x;
    int t = threadIdx.x;
    hr[t] = h[row * 256 + t];
    hr[t + 128] = h[row * 256 + 128 + t];
    __syncthreads();
    float acc = b[t];
#pragma unroll 4
    for (int k = 0; k < 256; ++k) acc += hr[k] * W[k * 128 + t];
    t1[row * 128 + t] = acc;
}

__global__ __launch_bounds__(64) void k_head2(const float* __restrict__ t1,
                                              const float* __restrict__ scsh,
                                              const float* __restrict__ W2,
                                              const float* __restrict__ b2,
                                              const float* __restrict__ W3,
                                              const float* __restrict__ b3,
                                              float* __restrict__ out) {
    __shared__ float v[128];
    int row = blockIdx.x, t = threadIdx.x;
    {
        float a = t1[row * 128 + t] * scsh[t] + scsh[128 + t];
        v[t] = fmaxf(a, 0.f);
        float a2 = t1[row * 128 + 64 + t] * scsh[64 + t] + scsh[192 + t];
        v[64 + t] = fmaxf(a2, 0.f);
    }
    __syncthreads();
    float acc = b2[t];
#pragma unroll 4
    for (int k = 0; k < 128; ++k) acc += v[k] * W2[k * 64 + t];
    float p = fmaxf(acc, 0.f) * W3[t];
    p += __shfl_xor(p, 1); p += __shfl_xor(p, 2); p += __shfl_xor(p, 4);
    p += __shfl_xor(p, 8); p += __shfl_xor(p, 16); p += __shfl_xor(p, 32);
    if (t == 0) out[row] = p + b3[0];
}

// ---------------- launch ----------------
extern "C" void kernel_launch(void* const* d_in, const int* in_sizes, int n_in,
                              void* d_out, int out_size, void* d_ws, size_t ws_size,
                              hipStream_t stream) {
    const float* x_in   = (const float*)d_in[0];
    const int*   ei     = (const int*)d_in[1];
    const int*   batch  = (const int*)d_in[2];
    const float* emb_W  = (const float*)d_in[3];
    const float* emb_b  = (const float*)d_in[4];
    const float* emb_g  = (const float*)d_in[5];
    const float* emb_be = (const float*)d_in[6];
    const float* gWl    = (const float*)d_in[7];
    const float* gWr    = (const float*)d_in[8];
    const float* gbl    = (const float*)d_in[9];
    const float* gbr    = (const float*)d_in[10];
    const float* gatt   = (const float*)d_in[11];
    const float* gbias  = (const float*)d_in[12];
    const float* gg     = (const float*)d_in[13];
    const float* gbe    = (const float*)d_in[14];
    const float* tWq    = (const float*)d_in[15];
    const float* tWk    = (const float*)d_in[16];
    const float* tWv    = (const float*)d_in[17];
    const float* tWs    = (const float*)d_in[18];
    const float* tbq    = (const float*)d_in[19];
    const float* tbk    = (const float*)d_in[20];
    const float* tbv    = (const float*)d_in[21];
    const float* tbs    = (const float*)d_in[22];
    const float* tg     = (const float*)d_in[23];
    const float* tbe    = (const float*)d_in[24];
    const float* oW1    = (const float*)d_in[25];
    const float* ob1    = (const float*)d_in[26];
    const float* og     = (const float*)d_in[27];
    const float* obe    = (const float*)d_in[28];
    const float* oW2    = (const float*)d_in[29];
    const float* ob2    = (const float*)d_in[30];
    const float* oW3    = (const float*)d_in[31];
    const float* ob3    = (const float*)d_in[32];
    float* out = (float*)d_out;

    const size_t NDsz = (size_t)NN * 128;
    float* x     = (float*)d_ws;
    float* bA    = x + NDsz;
    float* bB    = bA + NDsz;
    float* bC    = bB + NDsz;
    float* stats = bC + NDsz;        // 7 * 256 floats
    float* scsh  = stats + 7 * 256;  // 256 floats
    float* hpool = scsh + 256;       // 256*256
    float* t1    = hpool + 65536;    // 256*128
    __half* xlh  = (__half*)(t1 + 32768);   // NN*128 half (xl / K)
    __half* vh   = xlh + NDsz;              // NN*128 half (V)
    short* Wt    = (short*)(vh + NDsz);     // 12 * 128*128 bf16 transposed
    int* deg     = (int*)(Wt + 12 * 16384);
    int* rp      = deg + NN;
    int* cursor  = rp + NN + 1;
    int* colb    = cursor + NN;

    hipMemsetAsync(deg, 0, NN * sizeof(int), stream);
    hipMemsetAsync(stats, 0, 7 * 256 * sizeof(float), stream);

    // weight prep (bf16 transposed)
    k_prep<<<12, 256, 0, stream>>>(gWl, gWr, tWq, tWk, tWv, tWs, Wt);

    // CSR by destination
    k_deg<<<(NE + 255) / 256, 256, 0, stream>>>(ei, deg);
    k_scan<<<1, 1024, 0, stream>>>(deg, rp);
    hipMemcpyAsync(cursor, rp, NN * sizeof(int), hipMemcpyDeviceToDevice, stream);
    k_fill<<<(NE + 255) / 256, 256, 0, stream>>>(ei, cursor, colb);

    const int gGemm = (NN + 63) / 64;
    const int gStat = (NN + 255) / 256;
    const int gEdge = (NN + 3) / 4;

    // embedding + BN + relu
    k_gemm_emb<<<gGemm, 256, 0, stream>>>(x_in, emb_W, emb_b, bA, NN);
    k_stats<<<gStat, 256, 0, stream>>>(bA, NN, stats);
    k_finalize<<<1, 128, 0, stream>>>(stats, emb_g, emb_be, 1.f / NN, scsh);
    k_bn_apply<<<1024, 256, 0, stream>>>(x, bA, scsh, 1, 0);

    // 4 GATv2 layers
    for (int l = 0; l < NL; ++l) {
        k_gemm_mfma<1><<<gGemm, 256, 0, stream>>>(x, Wt + (size_t)l * 16384, gbl + l * 128, xlh, NN);
        k_gemm_mfma<0><<<gGemm, 256, 0, stream>>>(x, Wt + (size_t)(4 + l) * 16384, gbr + l * 128, bA, NN);
        k_gat_edge<<<gEdge, 256, 0, stream>>>(xlh, bA, gatt + l * 128, gbias + l * 128, rp, colb, bC);
        k_stats<<<gStat, 256, 0, stream>>>(bC, NN, stats + (1 + l) * 256);
        k_finalize<<<1, 128, 0, stream>>>(stats + (1 + l) * 256, gg + l * 128, gbe + l * 128, 1.f / NN, scsh);
        k_bn_apply<<<1024, 256, 0, stream>>>(x, bC, scsh, 1, 1);
    }

    // TransformerConv
    k_gemm_mfma<0><<<gGemm, 256, 0, stream>>>(x, Wt + (size_t)8 * 16384, tbq, bA, NN);   // q fp32
    k_gemm_mfma<1><<<gGemm, 256, 0, stream>>>(x, Wt + (size_t)9 * 16384, tbk, xlh, NN);  // k fp16
    k_gemm_mfma<1><<<gGemm, 256, 0, stream>>>(x, Wt + (size_t)10 * 16384, tbv, vh, NN);  // v fp16
    k_gemm_mfma<0><<<gGemm, 256, 0, stream>>>(x, Wt + (size_t)11 * 16384, tbs, bB, NN);  // skip fp32
    k_trans_edge<<<gEdge, 256, 0, stream>>>(bA, xlh, vh, bB, rp, colb, bC);
    k_stats<<<gStat, 256, 0, stream>>>(bC, NN, stats + 5 * 256);
    k_finalize<<<1, 128, 0, stream>>>(stats + 5 * 256, tg, tbe, 1.f / NN, scsh);
    k_bn_apply<<<1024, 256, 0, stream>>>(x, bC, scsh, 0, 1);

    // pooling + head
    k_pool<<<NG, 128, 0, stream>>>(x, batch, hpool);
    k_head1<<<NG, 128, 0, stream>>>(hpool, oW1, ob1, t1);
    k_stats<<<1, 256, 0, stream>>>(t1, NG, stats + 6 * 256);
    k_finalize<<<1, 128, 0, stream>>>(stats + 6 * 256, og, obe, 1.f / NG, scsh);
    k_head2<<<NG, 64, 0, stream>>>(t1, scsh, oW2, ob2, oW3, ob3, out);
}